// Round 8
// baseline (342.792 us; speedup 1.0000x reference)
//
#include <hip/hip_runtime.h>
#include <cmath>

#define DCOL 768
#define KCH 96            // DCOL/8
#define REG_ROWS 80
#define LDS_ROWS 19
#define FTHREADS 768

typedef __attribute__((ext_vector_type(8))) short bf16x8;

__device__ __forceinline__ short f2bf(float f) {
    return (short)(__builtin_bit_cast(unsigned, f) >> 16);
}
__device__ __forceinline__ float bf2f(short s) {
    unsigned u = ((unsigned)(unsigned short)s) << 16;
    return __builtin_bit_cast(float, u);
}

__device__ __forceinline__ int lower_bound_i(const int* __restrict__ arr, int n, int val) {
    int lo = 0, hi = n;
    while (lo < hi) {
        int mid = (lo + hi) >> 1;
        if (arr[mid] < val) lo = mid + 1; else hi = mid;
    }
    return lo;
}

// ---- reshape weights: fp32 src[k][j] -> bf16 W3[((jg*KCH + kk)*64 + j&63)*8 + ki]
// so a wave's GEMV step loads 64 lanes x 16B contiguous (1 KB coalesced).
__global__ void reshape_w(const float* __restrict__ src0, short* __restrict__ dst0,
                          const float* __restrict__ src1, short* __restrict__ dst1) {
    const float* __restrict__ src = blockIdx.z ? src1 : src0;
    short* __restrict__ dst = blockIdx.z ? dst1 : dst0;
    int t = blockIdx.x * 256 + threadIdx.x;     // [0, 12*KCH*64)
    int lane = t & 63;
    int kk8 = (t >> 6) % KCH;
    int jg = t / (KCH * 64);
    int j = jg * 64 + lane;
    bf16x8 w;
    #pragma unroll
    for (int ki = 0; ki < 8; ++ki)
        w[ki] = f2bf(src[(size_t)(kk8 * 8 + ki) * DCOL + j]);
    *(bf16x8*)(dst + (size_t)t * 8) = w;
}

// ---- GEMV dot: thread (wid,lane) computes output j = wid*64+lane.
// xs: LDS broadcast of the input vector (f32). W3 in the reshaped layout.
__device__ __forceinline__ float gemv_dot(const short* __restrict__ W3,
                                          const float* __restrict__ xs,
                                          int wid, int lane) {
    const bf16x8* __restrict__ wp = (const bf16x8*)W3 + (size_t)wid * (KCH * 64) + lane;
    float acc = 0.f;
    #pragma unroll 8
    for (int kk = 0; kk < KCH; ++kk) {
        bf16x8 w = wp[(size_t)kk * 64];
        const float* xk = xs + kk * 8;
        float4 xa = *(const float4*)(xk);
        float4 xb = *(const float4*)(xk + 4);
        acc += bf2f(w[0]) * xa.x + bf2f(w[1]) * xa.y + bf2f(w[2]) * xa.z + bf2f(w[3]) * xa.w
             + bf2f(w[4]) * xb.x + bf2f(w[5]) * xb.y + bf2f(w[6]) * xb.z + bf2f(w[7]) * xb.w;
    }
    return acc;
}

// ---- fully fused per-graph kernel: pool -> GEMV1(+relu,+vn) -> GEMV2 -> rows+y
// One block per graph; thread t owns column t. Graph rows held in 80 VGPRs +
// 19 LDS rows across the GEMVs so feat is read from HBM exactly once.
__global__ __launch_bounds__(FTHREADS, 3) void fused_kernel(
        const float* __restrict__ feat, const float* __restrict__ vn,
        const int* __restrict__ batch,
        const short* __restrict__ W3fc, const float* __restrict__ fcb,
        const short* __restrict__ W3p, const float* __restrict__ pb,
        float* __restrict__ out_feat, float* __restrict__ out_vn, int N) {
    __shared__ float ldsrows[LDS_ROWS][DCOL];   // 58368 B
    __shared__ float xbuf[DCOL];                // 3072 B
    __shared__ float x2buf[DCOL];               // 3072 B
    __shared__ int srange[2];

    const int g = blockIdx.x;
    const int t = threadIdx.x;
    if (t < 2) srange[t] = lower_bound_i(batch, N, g + t);
    __syncthreads();
    const int lo = srange[0], hi = srange[1];
    const int cnt = hi - lo;
    const float vnv = vn[(size_t)g * DCOL + t];

    const float* __restrict__ fp = feat + (size_t)lo * DCOL + t;
    const int nreg = cnt < REG_ROWS ? cnt : REG_ROWS;

    // phase 1a: load reg-held rows (independent loads pipeline), then sum
    float hold[REG_ROWS];
    #pragma unroll
    for (int i = 0; i < REG_ROWS; ++i)
        if (i < nreg) hold[i] = fp[(size_t)i * DCOL];

    float s0 = 0.f, s1 = 0.f, s2 = 0.f, s3 = 0.f;
    #pragma unroll
    for (int i = 0; i < REG_ROWS; i += 4) {
        if (i + 0 < nreg) s0 += hold[i + 0];
        if (i + 1 < nreg) s1 += hold[i + 1];
        if (i + 2 < nreg) s2 += hold[i + 2];
        if (i + 3 < nreg) s3 += hold[i + 3];
    }

    // phase 1b: LDS-held rows
    int nlds = cnt - REG_ROWS;
    nlds = nlds < 0 ? 0 : (nlds > LDS_ROWS ? LDS_ROWS : nlds);
    for (int i = 0; i < nlds; ++i) {
        float v = fp[(size_t)(REG_ROWS + i) * DCOL];
        ldsrows[i][t] = v;
        s0 += v;
    }
    // phase 1c: overflow rows (will be re-read in writeback; rare)
    for (int r = REG_ROWS + LDS_ROWS; r < cnt; ++r)
        s1 += fp[(size_t)r * DCOL];

    float sum = (s0 + s1) + (s2 + s3);
    float scale = cnt > 0 ? (logf((float)cnt) / (float)cnt) : 0.f;
    xbuf[t] = sum * scale + vnv;
    __syncthreads();

    // phase 2: GEMV1  h = relu(x @ fcW + fcb); vn_new = vn + h
    const int wid = t >> 6, lane = t & 63;
    float h = gemv_dot(W3fc, xbuf, wid, lane) + fcb[t];
    h = fmaxf(h, 0.f);
    float vnn = vnv + h;
    out_vn[(size_t)g * DCOL + t] = vnn;
    x2buf[t] = vnn;
    __syncthreads();

    // phase 3: GEMV2  y = vn_new @ pW + pb   (y[t] stays in thread t's register)
    float y = gemv_dot(W3p, x2buf, wid, lane) + pb[t];

    // phase 4: writeback rows + y (nt stores; feat not re-read except overflow)
    float* op = out_feat + (size_t)lo * DCOL + t;
    #pragma unroll
    for (int i = 0; i < REG_ROWS; ++i)
        if (i < nreg) __builtin_nontemporal_store(hold[i] + y, op + (size_t)i * DCOL);
    for (int i = 0; i < nlds; ++i)
        __builtin_nontemporal_store(ldsrows[i][t] + y, op + (size_t)(REG_ROWS + i) * DCOL);
    for (int r = REG_ROWS + LDS_ROWS; r < cnt; ++r)
        __builtin_nontemporal_store(fp[(size_t)r * DCOL] + y, op + (size_t)r * DCOL);
}

extern "C" void kernel_launch(void* const* d_in, const int* in_sizes, int n_in,
                              void* d_out, int out_size, void* d_ws, size_t ws_size,
                              hipStream_t stream) {
    const float* feat  = (const float*)d_in[0];
    const float* vn    = (const float*)d_in[1];
    const float* edge  = (const float*)d_in[2];
    const int*   batch = (const int*)d_in[3];
    const float* fcW   = (const float*)d_in[5];
    const float* fcb   = (const float*)d_in[6];
    const float* pW    = (const float*)d_in[7];
    const float* pb    = (const float*)d_in[8];

    const int D = in_sizes[6];            // 768
    const int N = in_sizes[0] / D;        // 100000
    const int B = in_sizes[1] / D;        // 1024
    const int edge_elems = in_sizes[2];   // B*DE

    float* out_feat = (float*)d_out;
    float* out_vn   = out_feat + (size_t)N * D;
    float* out_edge = out_vn + (size_t)B * D;

    char* ws = (char*)d_ws;
    short* W3fc = (short*)ws;                                 // [12*96*64*8] bf16
    short* W3p  = (short*)(ws + (size_t)12 * KCH * 64 * 8 * 2);

    // 0) reshape both weight matrices to the GEMV-coalesced bf16 layout
    dim3 rg(12 * KCH * 64 / 256, 1, 2);
    reshape_w<<<rg, 256, 0, stream>>>(fcW, W3fc, pW, W3p);

    // 1) fused pool + FC + project + broadcast-add (one block per graph)
    fused_kernel<<<B, FTHREADS, 0, stream>>>(feat, vn, batch, W3fc, fcb, W3p, pb,
                                             out_feat, out_vn, N);

    // 2) edge passthrough
    hipMemcpyAsync(out_edge, edge, (size_t)edge_elems * sizeof(float),
                   hipMemcpyDeviceToDevice, stream);
}

// Round 9
// 228.885 us; speedup vs baseline: 1.4977x; 1.4977x over previous
//
#include <hip/hip_runtime.h>
#include <cmath>

#define THREADS 256
#define PCOLS 192       // 768 floats / 4 = 192 float4 columns

typedef __attribute__((ext_vector_type(8))) short bf16x8;
typedef __attribute__((ext_vector_type(4))) float f32x4;

__device__ __forceinline__ short f2bf(float f) {
    return (short)(__builtin_bit_cast(unsigned, f) >> 16);
}
__device__ __forceinline__ short f2bf_rne(float f) {
    unsigned u = __builtin_bit_cast(unsigned, f);
    unsigned r = (u + 0x7fffu + ((u >> 16) & 1u)) >> 16;
    return (short)r;
}
__device__ __forceinline__ float bf2f(short s) {
    unsigned u = ((unsigned)(unsigned short)s) << 16;
    return __builtin_bit_cast(float, u);
}

typedef const __attribute__((address_space(1))) unsigned int* gas1_t;
typedef __attribute__((address_space(3))) unsigned int* las3_t;
__device__ __forceinline__ void gload16(const short* g, short* l) {
    __builtin_amdgcn_global_load_lds((gas1_t)g, (las3_t)l, 16, 0, 0);
}

__device__ __forceinline__ int lower_bound_i(const int* __restrict__ arr, int n, int val) {
    int lo = 0, hi = n;
    while (lo < hi) {
        int mid = (lo + hi) >> 1;
        if (arr[mid] < val) lo = mid + 1; else hi = mid;
    }
    return lo;
}

__device__ __forceinline__ float4 f4add(float4 a, float4 b) {
    a.x += b.x; a.y += b.y; a.z += b.z; a.w += b.w; return a;
}
__device__ __forceinline__ float4 f4fma(float4 a, float s, float4 b) {
    b.x += a.x * s; b.y += a.y * s; b.z += a.z * s; b.w += a.w * s; return b;
}
__device__ __forceinline__ float4 ldnt4(const float4* p) {
    f32x4 v = __builtin_nontemporal_load((const f32x4*)p);
    float4 r; r.x = v.x; r.y = v.y; r.z = v.z; r.w = v.w; return r;
}

// -------- transpose+convert: dst[n][k] (bf16) = src[k][n] (fp32), square n --------
__global__ void transpose_bf16(const float* __restrict__ src0, short* __restrict__ dst0,
                               const float* __restrict__ src1, short* __restrict__ dst1,
                               int n) {
    const float* src = blockIdx.z ? src1 : src0;
    short* dst = blockIdx.z ? dst1 : dst0;
    __shared__ short tile[32][33];
    int bx = blockIdx.x * 32, by = blockIdx.y * 32;
    int tx = threadIdx.x, ty = threadIdx.y;  // 32 x 8
    #pragma unroll
    for (int i = 0; i < 32; i += 8)
        tile[ty + i][tx] = f2bf(src[(size_t)(by + ty + i) * n + bx + tx]);
    __syncthreads();
    #pragma unroll
    for (int i = 0; i < 32; i += 8)
        dst[(size_t)(bx + ty + i) * n + by + tx] = tile[tx][ty + i];
}

// ---------------- pool: x_bf[g] = bf16( seg_mean(feat)*log(cnt) + vn[g] ) ----------
// SBF variant additionally writes a bf16 copy of feat (153 MB -> L3-resident)
// that node_add consumes instead of re-reading fp32 feat from HBM.
// fp32 feat loads are nt (don't evict the bf16 lines).
template <bool SBF>
__global__ void pool_kernel(const float4* __restrict__ feat4, const float4* __restrict__ vn4,
                            const int* __restrict__ batch, short* __restrict__ xbf,
                            short* __restrict__ featbf, int N, int D4) {
    int g = blockIdx.x;
    __shared__ int s_range[2];
    if (threadIdx.x < 2) s_range[threadIdx.x] = lower_bound_i(batch, N, g + (int)threadIdx.x);
    __syncthreads();
    int lo = s_range[0], hi = s_range[1];
    int cnt = hi - lo;
    float scale = (cnt > 0) ? (logf((float)cnt) / (float)cnt) : 0.f;

    int t = threadIdx.x;
    float4 a0 = {0,0,0,0}, a1 = {0,0,0,0}, a2 = {0,0,0,0}, a3 = {0,0,0,0};
    float4 a4 = {0,0,0,0}, a5 = {0,0,0,0}, a6 = {0,0,0,0}, a7 = {0,0,0,0};

    const float4* __restrict__ p = feat4 + (size_t)lo * D4 + t;
    short* __restrict__ pb = featbf + ((size_t)lo * D4 + t) * 4;
    const size_t rowb = (size_t)D4 * 4;
    int r = lo;
    for (; r + 8 <= hi; r += 8) {
        float4 v0 = ldnt4(p + 0 * (size_t)D4);
        float4 v1 = ldnt4(p + 1 * (size_t)D4);
        float4 v2 = ldnt4(p + 2 * (size_t)D4);
        float4 v3 = ldnt4(p + 3 * (size_t)D4);
        float4 v4 = ldnt4(p + 4 * (size_t)D4);
        float4 v5 = ldnt4(p + 5 * (size_t)D4);
        float4 v6 = ldnt4(p + 6 * (size_t)D4);
        float4 v7 = ldnt4(p + 7 * (size_t)D4);
        if (SBF) {
            float4 vv[8] = {v0, v1, v2, v3, v4, v5, v6, v7};
            #pragma unroll
            for (int k = 0; k < 8; ++k) {
                short4 o;
                o.x = f2bf_rne(vv[k].x); o.y = f2bf_rne(vv[k].y);
                o.z = f2bf_rne(vv[k].z); o.w = f2bf_rne(vv[k].w);
                *(short4*)(pb + (size_t)k * rowb) = o;
            }
        }
        a0 = f4add(a0, v0); a1 = f4add(a1, v1); a2 = f4add(a2, v2); a3 = f4add(a3, v3);
        a4 = f4add(a4, v4); a5 = f4add(a5, v5); a6 = f4add(a6, v6); a7 = f4add(a7, v7);
        p += 8 * (size_t)D4;
        pb += 8 * rowb;
    }
    for (; r < hi; ++r) {
        float4 v = ldnt4(p);
        if (SBF) {
            short4 o;
            o.x = f2bf_rne(v.x); o.y = f2bf_rne(v.y);
            o.z = f2bf_rne(v.z); o.w = f2bf_rne(v.w);
            *(short4*)pb = o;
        }
        a0 = f4add(a0, v);
        p += D4;
        pb += rowb;
    }
    float4 s = f4add(f4add(f4add(a0, a1), f4add(a2, a3)), f4add(f4add(a4, a5), f4add(a6, a7)));
    float4 vnv = vn4[(size_t)g * D4 + t];
    float4 x = f4fma(s, scale, vnv);
    short4 o;
    o.x = f2bf(x.x); o.y = f2bf(x.y); o.z = f2bf(x.z); o.w = f2bf(x.w);
    *(short4*)(xbf + ((size_t)g * D4 + t) * 4) = o;
}

// ---------------- bf16-native MFMA GEMM ----------------
template <bool RELU, bool ADD_RES, bool WRITE_BF>
__global__ __launch_bounds__(256) void gemm_bf(const short* __restrict__ A,
        const short* __restrict__ Wt, const float* __restrict__ bias,
        const float* __restrict__ res, float* __restrict__ out,
        short* __restrict__ out_bf, int Nn, int K) {
    __shared__ short lds[2][2][64 * 32];
    const int tid = threadIdx.x;
    const int lane = tid & 63;
    const int wid = tid >> 6;
    const int wr = wid >> 1, wc = wid & 1;
    const int lrow = lane & 15;
    const int kg = lane >> 4;
    const int tileM = blockIdx.y * 64;
    const int tileN = blockIdx.x * 64;
    const int nk = K / 32;

    f32x4 acc[2][2] = {};

    const int srow = tid >> 2;
    const int sci = (tid & 3) ^ (srow & 3);

    #define STG(buf, kt) do {                                                    \
        short* La = lds[buf][0];                                                 \
        short* Lb = lds[buf][1];                                                 \
        gload16(A  + (size_t)(tileM + srow) * K + (kt) * 32 + sci * 8, La + tid * 8); \
        gload16(Wt + (size_t)(tileN + srow) * K + (kt) * 32 + sci * 8, Lb + tid * 8); \
    } while (0)

    STG(0, 0);
    __syncthreads();

    for (int kt = 0; kt < nk; ++kt) {
        if (kt + 1 < nk) STG((kt + 1) & 1, kt + 1);
        const short* La = lds[kt & 1][0];
        const short* Lb = lds[kt & 1][1];
        bf16x8 a[2], b[2];
        #pragma unroll
        for (int m = 0; m < 2; ++m) {
            int row = wr * 32 + m * 16 + lrow;
            a[m] = *(const bf16x8*)(La + row * 32 + ((kg ^ (row & 3)) * 8));
        }
        #pragma unroll
        for (int n = 0; n < 2; ++n) {
            int col = wc * 32 + n * 16 + lrow;
            b[n] = *(const bf16x8*)(Lb + col * 32 + ((kg ^ (col & 3)) * 8));
        }
        #pragma unroll
        for (int m = 0; m < 2; ++m)
            #pragma unroll
            for (int n = 0; n < 2; ++n)
                acc[m][n] = __builtin_amdgcn_mfma_f32_16x16x32_bf16(a[m], b[n], acc[m][n], 0, 0, 0);
        __syncthreads();
    }

    #pragma unroll
    for (int m = 0; m < 2; ++m) {
        #pragma unroll
        for (int n = 0; n < 2; ++n) {
            int col = tileN + wc * 32 + n * 16 + lrow;
            float bv = bias[col];
            #pragma unroll
            for (int r = 0; r < 4; ++r) {
                int row = tileM + wr * 32 + m * 16 + kg * 4 + r;
                float v = acc[m][n][r] + bv;
                if (RELU) v = fmaxf(v, 0.f);
                if (ADD_RES) v += res[(size_t)row * Nn + col];
                out[(size_t)row * Nn + col] = v;
                if (WRITE_BF) out_bf[(size_t)row * Nn + col] = f2bf(v);
            }
        }
    }
    #undef STG
}

// ---------------- node_add (bf16 path): out[node] = bf16feat[node] + y[batch[node]] --
// featbf (153 MB) should be largely L3-resident from pool's pass.
__global__ void node_add_bf(const short* __restrict__ featbf, const float* __restrict__ y,
                            const int* __restrict__ batch, float* __restrict__ out, int N) {
    int node = blockIdx.x * blockDim.y + threadIdx.y;
    if (node >= N) return;
    int t = threadIdx.x;                       // 0..95, 8 cols each
    int b = batch[node];
    bf16x8 f = *(const bf16x8*)(featbf + (size_t)node * 768 + t * 8);
    const float* yp = y + (size_t)b * 768 + t * 8;
    float4 ya = *(const float4*)yp;
    float4 yb = *(const float4*)(yp + 4);
    f32x4 r0, r1;
    r0.x = bf2f(f[0]) + ya.x; r0.y = bf2f(f[1]) + ya.y;
    r0.z = bf2f(f[2]) + ya.z; r0.w = bf2f(f[3]) + ya.w;
    r1.x = bf2f(f[4]) + yb.x; r1.y = bf2f(f[5]) + yb.y;
    r1.z = bf2f(f[6]) + yb.z; r1.w = bf2f(f[7]) + yb.w;
    float* op = out + (size_t)node * 768 + t * 8;
    __builtin_nontemporal_store(r0, (f32x4*)op);
    __builtin_nontemporal_store(r1, (f32x4*)(op + 4));
}

// ---------------- node_add fallback (fp32 path, round-7 proven) ----------------
__global__ void node_add_kernel(const float4* __restrict__ feat4, const float4* __restrict__ y4,
                                const int* __restrict__ batch, float* __restrict__ out,
                                int N, int D4) {
    int node = (int)(blockIdx.x * blockDim.y + threadIdx.y);
    if (node >= N) return;
    int t = threadIdx.x;
    int b = batch[node];
    size_t idx = (size_t)node * D4 + t;
    float4 f = feat4[idx];
    float4 v = y4[(size_t)b * D4 + t];
    f32x4 r;
    r.x = f.x + v.x; r.y = f.y + v.y; r.z = f.z + v.z; r.w = f.w + v.w;
    __builtin_nontemporal_store(r, (f32x4*)(out + idx * 4));
}

extern "C" void kernel_launch(void* const* d_in, const int* in_sizes, int n_in,
                              void* d_out, int out_size, void* d_ws, size_t ws_size,
                              hipStream_t stream) {
    const float* feat  = (const float*)d_in[0];
    const float* vn    = (const float*)d_in[1];
    const float* edge  = (const float*)d_in[2];
    const int*   batch = (const int*)d_in[3];
    const float* fcW   = (const float*)d_in[5];
    const float* fcb   = (const float*)d_in[6];
    const float* pW    = (const float*)d_in[7];
    const float* pb    = (const float*)d_in[8];

    const int D = in_sizes[6];            // 768
    const int N = in_sizes[0] / D;        // 100000
    const int B = in_sizes[1] / D;        // 1024
    const int edge_elems = in_sizes[2];   // B*DE
    const int D4 = D / 4;                 // 192

    float* out_feat = (float*)d_out;
    float* out_vn   = out_feat + (size_t)N * D;
    float* out_edge = out_vn + (size_t)B * D;

    char* ws = (char*)d_ws;
    size_t off = 0;
    short* xbf  = (short*)(ws + off); off += (size_t)B * D * 2;
    short* x2bf = (short*)(ws + off); off += (size_t)B * D * 2;
    short* fcWt = (short*)(ws + off); off += (size_t)D * D * 2;
    short* pWt  = (short*)(ws + off); off += (size_t)D * D * 2;
    float* y    = (float*)(ws + off); off += (size_t)B * D * 4;
    short* featbf = (short*)(ws + off);
    const bool use_bf = (ws_size >= off + (size_t)N * D * 2);

    // 0) weights -> transposed bf16
    dim3 tb(32, 8);
    dim3 tg(D / 32, D / 32, 2);
    transpose_bf16<<<tg, tb, 0, stream>>>(fcW, fcWt, pW, pWt, D);

    // 1) pool + vn add -> x (bf16); optionally emit bf16 feat copy
    if (use_bf)
        pool_kernel<true><<<B, PCOLS, 0, stream>>>((const float4*)feat, (const float4*)vn,
                                                   batch, xbf, featbf, N, D4);
    else
        pool_kernel<false><<<B, PCOLS, 0, stream>>>((const float4*)feat, (const float4*)vn,
                                                    batch, xbf, nullptr, N, D4);

    // 2) vn_new = vn + relu(x @ fcW + fcb) -> out_vn (f32) + x2 (bf16)
    dim3 gdim(D / 64, B / 64);
    gemm_bf<true, true, true><<<gdim, THREADS, 0, stream>>>(xbf, fcWt, fcb, vn,
                                                            out_vn, x2bf, D, D);

    // 3) y = vn_new @ pW + pb
    gemm_bf<false, false, false><<<gdim, THREADS, 0, stream>>>(x2bf, pWt, pb, nullptr,
                                                               y, nullptr, D, D);

    // 4) feat_out = feat + y[batch]
    if (use_bf) {
        dim3 nblk(96, 8);
        node_add_bf<<<(N + 7) / 8, nblk, 0, stream>>>(featbf, y, batch, out_feat, N);
    } else {
        dim3 nblk(192, 2);
        node_add_kernel<<<(N + 1) / 2, nblk, 0, stream>>>((const float4*)feat, (const float4*)y,
                                                          batch, out_feat, N, D4);
    }

    // 5) edge passthrough
    hipMemcpyAsync(out_edge, edge, (size_t)edge_elems * sizeof(float),
                   hipMemcpyDeviceToDevice, stream);
}